// Round 6
// baseline (218.326 us; speedup 1.0000x reference)
//
#include <hip/hip_runtime.h>

namespace {

typedef float f32x4 __attribute__((ext_vector_type(4)));

constexpr int S   = 32;    // neighbors
constexpr int F   = 128;   // features
constexpr int BR  = 32;    // rows per block (8 per wave)
constexpr int TPB = 256;   // 4 waves

// ---- Batcher odd-even mergesort network for 16 elements (63 CEs) ----
struct CEPair { int a, b; };

constexpr int batcher_count16() {
  int n = 16, cnt = 0;
  for (int p = 1; p < n; p <<= 1)
    for (int k = p; k >= 1; k >>= 1)
      for (int j = k % p; j + k < n; j += 2 * k)
        for (int i = 0; i < k && i + j + k < n; ++i)
          if ((i + j) / (2 * p) == (i + j + k) / (2 * p))
            ++cnt;
  return cnt;
}
constexpr int NCE = batcher_count16();   // 63

struct Net16 { CEPair ce[NCE]; };

constexpr Net16 make_net16() {
  Net16 net{};
  int n = 16, c = 0;
  for (int p = 1; p < n; p <<= 1)
    for (int k = p; k >= 1; k >>= 1)
      for (int j = k % p; j + k < n; j += 2 * k)
        for (int i = 0; i < k && i + j + k < n; ++i)
          if ((i + j) / (2 * p) == (i + j + k) / (2 * p))
            net.ce[c++] = CEPair{i + j, i + j + k};
  return net;
}
constexpr Net16 NET16 = make_net16();

template<int T>
__device__ __forceinline__ void sort16(float (&v)[16]) {
  if constexpr (T < NCE) {
    constexpr int a = NET16.ce[T].a;
    constexpr int b = NET16.ce[T].b;
    float x = v[a], y = v[b];
    v[a] = fminf(x, y);
    v[b] = fmaxf(x, y);
    sort16<T + 1>(v);
  }
}

// Issue one HALF-row (32 neighbors x 64 features; lane = one feature).
// 32 regular (cached) loads of 256B each + one x element. No waits here —
// consumers rely on compiler-counted vmcnt, keeping other chunks in flight.
__device__ __forceinline__ void issue_half(const float* __restrict__ neigh,
                                           const float* __restrict__ x,
                                           int row, int h, int lane,
                                           float (&A)[16], float (&B)[16],
                                           float& xv)
{
    const float* nb = neigh + (size_t)row * (S * F) + h * 64 + lane;
#pragma unroll
    for (int s = 0; s < 16; ++s) A[s] = nb[s * F];
#pragma unroll
    for (int s = 0; s < 16; ++s) B[s] = nb[(s + 16) * F];
    xv = x[(size_t)row * F + h * 64 + lane];
}

// rank-16 (0-indexed) of 32 = min_{i=1..16} max(A[i-1], B[16-i])
__device__ __forceinline__ void select_store(float (&A)[16], float (&B)[16],
                                             float xv,
                                             float* __restrict__ msrow,
                                             float* __restrict__ xsrow,
                                             int h, int lane)
{
    sort16<0>(A);
    sort16<0>(B);
#pragma unroll
    for (int q = 0; q < 16; ++q) A[q] = fmaxf(A[q], B[15 - q]);
#pragma unroll
    for (int st = 8; st >= 1; st >>= 1)
#pragma unroll
        for (int q = 0; q < st; ++q) A[q] = fminf(A[q], A[q + st]);
    msrow[h * 64 + lane] = A[0];
    xsrow[h * 64 + lane] = xv;
}

// Barrier-free, wave-owned rows. 2-deep ping-pong prefetch over 16 HALF-row
// chunks (8KB each): half-chunk i+1's 33 loads are outstanding while chunk i
// sorts. Half-size slots keep buffer VGPRs at 64 -> fits 4 waves/SIMD.
__global__ __launch_bounds__(TPB, 4) void fused_median_gemm(
    const float* __restrict__ x,
    const float* __restrict__ neigh,
    const float* __restrict__ Ks,
    const float* __restrict__ Kn,
    const float* __restrict__ bias,
    float* __restrict__ out,
    int N)
{
    __shared__ __align__(16) float xs[4][8][F];   // 16 KB
    __shared__ __align__(16) float ms[4][8][F];   // 16 KB

    const int tid  = threadIdx.x;
    const int wv   = tid >> 6;                    // wave id 0..3
    const int lane = tid & 63;                    // feature within half
    const int row0 = blockIdx.x * BR + wv * 8;

    const int rmax = N - 1;
    auto rw = [&](int hp) { int r = row0 + (hp >> 1); return r > rmax ? rmax : r; };

    // ---------- Phase A: pipelined rank-16-of-32, 16 half-row chunks ----------
    {
        float A0[16], B0[16], A1[16], B1[16];
        float x0, x1;

        issue_half(neigh, x, rw(0), 0, lane, A0, B0, x0);
#pragma unroll 1
        for (int p = 0; p < 8; ++p) {
            const int h0 = (2 * p) & 1, h1 = (2 * p + 1) & 1;   // 0,1
            issue_half(neigh, x, rw(2 * p + 1), 1, lane, A1, B1, x1);
            select_store(A0, B0, x0, &ms[wv][(2 * p) >> 1][0],
                         &xs[wv][(2 * p) >> 1][0], h0, lane);
            if (p < 7)
                issue_half(neigh, x, rw(2 * p + 2), 0, lane, A0, B0, x0);
            select_store(A1, B1, x1, &ms[wv][(2 * p + 1) >> 1][0],
                         &xs[wv][(2 * p + 1) >> 1][0], h1, lane);
        }
    }

    // drain this wave's LDS writes only (NOT vmcnt, NOT a barrier)
    asm volatile("s_waitcnt lgkmcnt(0)" ::: "memory");

    // ---------- Phase B: GEMM for this wave's 8 rows ----------
    // lane -> 4 output cols; lanes 0..31 self-half, 32..63 neigh-half
    const bool self_half = (lane < 32);
    const float* __restrict__ W = self_half ? Ks : Kn;
    const int wcol = (lane * 4) & 127;
    const float* lin = self_half ? &xs[wv][0][0] : &ms[wv][0][0];

    f32x4 acc[8];
#pragma unroll
    for (int r = 0; r < 8; ++r) acc[r] = f32x4{0.f, 0.f, 0.f, 0.f};

#pragma unroll 4
    for (int k4 = 0; k4 < 32; ++k4) {
        f32x4 wv4[4];
#pragma unroll
        for (int dk = 0; dk < 4; ++dk)
            wv4[dk] = *(const f32x4*)&W[(k4 * 4 + dk) * 128 + wcol];

        f32x4 xr[8];
#pragma unroll
        for (int r = 0; r < 8; ++r)
            xr[r] = *(const f32x4*)&lin[r * F + k4 * 4];   // wave-broadcast LDS read

#pragma unroll
        for (int r = 0; r < 8; ++r) {
#pragma unroll
            for (int dk = 0; dk < 4; ++dk) {
                const float s = xr[r][dk];
                acc[r].x = fmaf(s, wv4[dk].x, acc[r].x);
                acc[r].y = fmaf(s, wv4[dk].y, acc[r].y);
                acc[r].z = fmaf(s, wv4[dk].z, acc[r].z);
                acc[r].w = fmaf(s, wv4[dk].w, acc[r].w);
            }
        }
    }

    const f32x4 bv = *(const f32x4*)&bias[lane * 4];
#pragma unroll
    for (int r = 0; r < 8; ++r) {
        int row = row0 + r;
        if (row > rmax) row = rmax;   // duplicate store of identical values; benign
        f32x4 o;
        o.x = fmaxf(acc[r].x + bv.x, 0.f);
        o.y = fmaxf(acc[r].y + bv.y, 0.f);
        o.z = fmaxf(acc[r].z + bv.z, 0.f);
        o.w = fmaxf(acc[r].w + bv.w, 0.f);
        __builtin_nontemporal_store(o, (f32x4*)&out[(size_t)row * 256 + lane * 4]);
    }
}

} // namespace

extern "C" void kernel_launch(void* const* d_in, const int* in_sizes, int n_in,
                              void* d_out, int out_size, void* d_ws, size_t ws_size,
                              hipStream_t stream) {
    const float* x     = (const float*)d_in[0];
    const float* neigh = (const float*)d_in[1];
    const float* Ks    = (const float*)d_in[2];
    const float* Kn    = (const float*)d_in[3];
    const float* bias  = (const float*)d_in[4];
    float* out = (float*)d_out;

    const int N = in_sizes[0] / F;   // 50000
    const int grid = (N + BR - 1) / BR;
    hipLaunchKernelGGL(fused_median_gemm, dim3(grid), dim3(TPB), 0, stream,
                       x, neigh, Ks, Kn, bias, out, N);
}

// Round 7
// 196.603 us; speedup vs baseline: 1.1105x; 1.1105x over previous
//
#include <hip/hip_runtime.h>

namespace {

typedef float f32x4 __attribute__((ext_vector_type(4)));

constexpr int S   = 32;    // neighbors
constexpr int F   = 128;   // features
constexpr int BR  = 32;    // rows per block (8 per wave)
constexpr int TPB = 256;   // 4 waves

// ---- Batcher odd-even mergesort network for 16 elements (63 CEs) ----
struct CEPair { int a, b; };

constexpr int batcher_count16() {
  int n = 16, cnt = 0;
  for (int p = 1; p < n; p <<= 1)
    for (int k = p; k >= 1; k >>= 1)
      for (int j = k % p; j + k < n; j += 2 * k)
        for (int i = 0; i < k && i + j + k < n; ++i)
          if ((i + j) / (2 * p) == (i + j + k) / (2 * p))
            ++cnt;
  return cnt;
}
constexpr int NCE = batcher_count16();   // 63

struct Net16 { CEPair ce[NCE]; };

constexpr Net16 make_net16() {
  Net16 net{};
  int n = 16, c = 0;
  for (int p = 1; p < n; p <<= 1)
    for (int k = p; k >= 1; k >>= 1)
      for (int j = k % p; j + k < n; j += 2 * k)
        for (int i = 0; i < k && i + j + k < n; ++i)
          if ((i + j) / (2 * p) == (i + j + k) / (2 * p))
            net.ce[c++] = CEPair{i + j, i + j + k};
  return net;
}
constexpr Net16 NET16 = make_net16();

template<int T>
__device__ __forceinline__ void sort16(float (&v)[16]) {
  if constexpr (T < NCE) {
    constexpr int a = NET16.ce[T].a;
    constexpr int b = NET16.ce[T].b;
    float x = v[a], y = v[b];
    v[a] = fminf(x, y);
    v[b] = fmaxf(x, y);
    sort16<T + 1>(v);
  }
}

// Issue one HALF-row (32 neighbors x 64 features; lane = one feature).
// 32 NONTEMPORAL loads of 256B each + one x element. No waits here —
// consumers rely on compiler-counted vmcnt, keeping other chunks in flight.
__device__ __forceinline__ void issue_half(const float* __restrict__ neigh,
                                           const float* __restrict__ x,
                                           int row, int h, int lane,
                                           float (&A)[16], float (&B)[16],
                                           float& xv)
{
    const float* nb = neigh + (size_t)row * (S * F) + h * 64 + lane;
#pragma unroll
    for (int s = 0; s < 16; ++s)
        A[s] = __builtin_nontemporal_load(nb + s * F);
#pragma unroll
    for (int s = 0; s < 16; ++s)
        B[s] = __builtin_nontemporal_load(nb + (s + 16) * F);
    xv = x[(size_t)row * F + h * 64 + lane];
}

// rank-16 (0-indexed) of 32 = min_{i=1..16} max(A[i-1], B[16-i])
__device__ __forceinline__ void select_store(float (&A)[16], float (&B)[16],
                                             float xv,
                                             float* __restrict__ msrow,
                                             float* __restrict__ xsrow,
                                             int h, int lane)
{
    sort16<0>(A);
    sort16<0>(B);
#pragma unroll
    for (int q = 0; q < 16; ++q) A[q] = fmaxf(A[q], B[15 - q]);
#pragma unroll
    for (int st = 8; st >= 1; st >>= 1)
#pragma unroll
        for (int q = 0; q < st; ++q) A[q] = fminf(A[q], A[q + st]);
    msrow[h * 64 + lane] = A[0];
    xsrow[h * 64 + lane] = xv;
}

// Barrier-free, wave-owned rows. 2-deep ping-pong prefetch over 16 HALF-row
// chunks (8KB each): half-chunk i+1's 33 loads are outstanding while chunk i
// sorts. Half-size slots keep buffer VGPRs at 64 -> fits 4 waves/SIMD.
__global__ __launch_bounds__(TPB, 4) void fused_median_gemm(
    const float* __restrict__ x,
    const float* __restrict__ neigh,
    const float* __restrict__ Ks,
    const float* __restrict__ Kn,
    const float* __restrict__ bias,
    float* __restrict__ out,
    int N)
{
    __shared__ __align__(16) float xs[4][8][F];   // 16 KB
    __shared__ __align__(16) float ms[4][8][F];   // 16 KB

    const int tid  = threadIdx.x;
    const int wv   = tid >> 6;                    // wave id 0..3
    const int lane = tid & 63;                    // feature within half
    const int row0 = blockIdx.x * BR + wv * 8;

    const int rmax = N - 1;
    auto rw = [&](int hp) { int r = row0 + (hp >> 1); return r > rmax ? rmax : r; };

    // ---------- Phase A: pipelined rank-16-of-32, 16 half-row chunks ----------
    {
        float A0[16], B0[16], A1[16], B1[16];
        float x0, x1;

        issue_half(neigh, x, rw(0), 0, lane, A0, B0, x0);
#pragma unroll 1
        for (int p = 0; p < 8; ++p) {
            const int h0 = (2 * p) & 1, h1 = (2 * p + 1) & 1;   // 0,1
            issue_half(neigh, x, rw(2 * p + 1), 1, lane, A1, B1, x1);
            select_store(A0, B0, x0, &ms[wv][(2 * p) >> 1][0],
                         &xs[wv][(2 * p) >> 1][0], h0, lane);
            if (p < 7)
                issue_half(neigh, x, rw(2 * p + 2), 0, lane, A0, B0, x0);
            select_store(A1, B1, x1, &ms[wv][(2 * p + 1) >> 1][0],
                         &xs[wv][(2 * p + 1) >> 1][0], h1, lane);
        }
    }

    // drain this wave's LDS writes only (NOT vmcnt, NOT a barrier)
    asm volatile("s_waitcnt lgkmcnt(0)" ::: "memory");

    // ---------- Phase B: GEMM for this wave's 8 rows ----------
    // lane -> 4 output cols; lanes 0..31 self-half, 32..63 neigh-half
    const bool self_half = (lane < 32);
    const float* __restrict__ W = self_half ? Ks : Kn;
    const int wcol = (lane * 4) & 127;
    const float* lin = self_half ? &xs[wv][0][0] : &ms[wv][0][0];

    f32x4 acc[8];
#pragma unroll
    for (int r = 0; r < 8; ++r) acc[r] = f32x4{0.f, 0.f, 0.f, 0.f};

#pragma unroll 4
    for (int k4 = 0; k4 < 32; ++k4) {
        f32x4 wv4[4];
#pragma unroll
        for (int dk = 0; dk < 4; ++dk)
            wv4[dk] = *(const f32x4*)&W[(k4 * 4 + dk) * 128 + wcol];

        f32x4 xr[8];
#pragma unroll
        for (int r = 0; r < 8; ++r)
            xr[r] = *(const f32x4*)&lin[r * F + k4 * 4];   // wave-broadcast LDS read

#pragma unroll
        for (int r = 0; r < 8; ++r) {
#pragma unroll
            for (int dk = 0; dk < 4; ++dk) {
                const float s = xr[r][dk];
                acc[r].x = fmaf(s, wv4[dk].x, acc[r].x);
                acc[r].y = fmaf(s, wv4[dk].y, acc[r].y);
                acc[r].z = fmaf(s, wv4[dk].z, acc[r].z);
                acc[r].w = fmaf(s, wv4[dk].w, acc[r].w);
            }
        }
    }

    const f32x4 bv = *(const f32x4*)&bias[lane * 4];
#pragma unroll
    for (int r = 0; r < 8; ++r) {
        int row = row0 + r;
        if (row > rmax) row = rmax;   // duplicate store of identical values; benign
        f32x4 o;
        o.x = fmaxf(acc[r].x + bv.x, 0.f);
        o.y = fmaxf(acc[r].y + bv.y, 0.f);
        o.z = fmaxf(acc[r].z + bv.z, 0.f);
        o.w = fmaxf(acc[r].w + bv.w, 0.f);
        __builtin_nontemporal_store(o, (f32x4*)&out[(size_t)row * 256 + lane * 4]);
    }
}

} // namespace

extern "C" void kernel_launch(void* const* d_in, const int* in_sizes, int n_in,
                              void* d_out, int out_size, void* d_ws, size_t ws_size,
                              hipStream_t stream) {
    const float* x     = (const float*)d_in[0];
    const float* neigh = (const float*)d_in[1];
    const float* Ks    = (const float*)d_in[2];
    const float* Kn    = (const float*)d_in[3];
    const float* bias  = (const float*)d_in[4];
    float* out = (float*)d_out;

    const int N = in_sizes[0] / F;   // 50000
    const int grid = (N + BR - 1) / BR;
    hipLaunchKernelGGL(fused_median_gemm, dim3(grid), dim3(TPB), 0, stream,
                       x, neigh, Ks, Kn, bias, out, N);
}

// Round 8
// 192.893 us; speedup vs baseline: 1.1319x; 1.0192x over previous
//
#include <hip/hip_runtime.h>

namespace {

typedef float  f32x2  __attribute__((ext_vector_type(2)));
typedef float  f32x4  __attribute__((ext_vector_type(4)));
typedef short  bf16x8 __attribute__((ext_vector_type(8)));
typedef unsigned short u16;

constexpr int S   = 32;    // neighbors
constexpr int F   = 128;   // features
constexpr int BR  = 32;    // rows per block (8 per wave)
constexpr int TPB = 256;   // 4 waves

// ---- Batcher odd-even mergesort network for 16 elements (63 CEs) ----
struct CEPair { int a, b; };

constexpr int batcher_count16() {
  int n = 16, cnt = 0;
  for (int p = 1; p < n; p <<= 1)
    for (int k = p; k >= 1; k >>= 1)
      for (int j = k % p; j + k < n; j += 2 * k)
        for (int i = 0; i < k && i + j + k < n; ++i)
          if ((i + j) / (2 * p) == (i + j + k) / (2 * p))
            ++cnt;
  return cnt;
}
constexpr int NCE = batcher_count16();   // 63

struct Net16 { CEPair ce[NCE]; };

constexpr Net16 make_net16() {
  Net16 net{};
  int n = 16, c = 0;
  for (int p = 1; p < n; p <<= 1)
    for (int k = p; k >= 1; k >>= 1)
      for (int j = k % p; j + k < n; j += 2 * k)
        for (int i = 0; i < k && i + j + k < n; ++i)
          if ((i + j) / (2 * p) == (i + j + k) / (2 * p))
            net.ce[c++] = CEPair{i + j, i + j + k};
  return net;
}
constexpr Net16 NET16 = make_net16();

__device__ __forceinline__ f32x2 min2(f32x2 a, f32x2 b) {
  f32x2 r; r.x = fminf(a.x, b.x); r.y = fminf(a.y, b.y); return r;
}
__device__ __forceinline__ f32x2 max2(f32x2 a, f32x2 b) {
  f32x2 r; r.x = fmaxf(a.x, b.x); r.y = fmaxf(a.y, b.y); return r;
}

template<int T>
__device__ __forceinline__ void sort16(f32x2 (&v)[16]) {
  if constexpr (T < NCE) {
    constexpr int a = NET16.ce[T].a;
    constexpr int b = NET16.ce[T].b;
    f32x2 x = v[a], y = v[b];
    v[a] = min2(x, y);
    v[b] = max2(x, y);
    sort16<T + 1>(v);
  }
}

// fp32 -> bf16 with round-to-nearest-even (values here are finite)
__device__ __forceinline__ unsigned f2bf(float f) {
  unsigned u = __builtin_bit_cast(unsigned, f);
  return (u + 0x7FFFu + ((u >> 16) & 1u)) >> 16;
}

// issue one row's 32 neighbor half-loads + x chunk (NO wait here; consumers
// wait via compiler-counted vmcnt, leaving other rows' loads in flight)
__device__ __forceinline__ void issue_row(const float* __restrict__ neigh,
                                          const float* __restrict__ x,
                                          int row, int lane,
                                          f32x2 (&A)[16], f32x2 (&B)[16],
                                          f32x2& xv)
{
    const f32x2* nb = (const f32x2*)(neigh + (size_t)row * (S * F)) + lane;
#pragma unroll
    for (int s = 0; s < 16; ++s)
        A[s] = __builtin_nontemporal_load(nb + (size_t)s * 64);
#pragma unroll
    for (int s = 0; s < 16; ++s)
        B[s] = __builtin_nontemporal_load(nb + (size_t)(s + 16) * 64);
    xv = *((const f32x2*)(x + (size_t)row * F) + lane);
}

// rank-16-of-32 (0-indexed) via two sorted 16-runs + in-place merge-select.
// Stores median + x as PACKED BF16 (2 per uint) for the MFMA phase.
__device__ __forceinline__ void select_store(f32x2 (&A)[16], f32x2 (&B)[16],
                                             f32x2 xv,
                                             u16* __restrict__ msrow,
                                             u16* __restrict__ xsrow,
                                             int lane)
{
    sort16<0>(A);
    sort16<0>(B);
#pragma unroll
    for (int q = 0; q < 16; ++q) A[q] = max2(A[q], B[15 - q]);
#pragma unroll
    for (int st = 8; st >= 1; st >>= 1)
#pragma unroll
        for (int q = 0; q < st; ++q) A[q] = min2(A[q], A[q + st]);
    ((unsigned*)msrow)[lane] = f2bf(A[0].x) | (f2bf(A[0].y) << 16);
    ((unsigned*)xsrow)[lane] = f2bf(xv.x)   | (f2bf(xv.y)   << 16);
}

// --- tiny pre-kernel: convert both weight matrices to bf16 and swizzle into
// MFMA B-fragment order. Chunk (c,kk) holds the fragment for col-tile c
// (cols c*16..c*16+15 of the concatenated 256-col output) and k-block kk
// (k = kk*32 .. kk*32+31): lane l's 8 contiguous bf16 = W[kk*32+(l>>4)*8+j][n],
// n = c*16 + (l&15). One coalesced 16B load per fragment in the main kernel.
__global__ void convert_weights(const float* __restrict__ Ks,
                                const float* __restrict__ Kn,
                                u16* __restrict__ wsb)
{
    const int t  = blockIdx.x * 256 + threadIdx.x;   // 0..4095
    const int c  = t >> 8;          // col-tile 0..15
    const int kk = (t >> 6) & 3;    // k-block 0..3
    const int l  = t & 63;          // lane
    const int n  = c * 16 + (l & 15);
    const int kb = kk * 32 + (l >> 4) * 8;
    const float* __restrict__ W = (n < 128) ? Ks : Kn;
    const int nn = n & 127;

    u16 tmp[8];
#pragma unroll
    for (int j = 0; j < 8; ++j)
        tmp[j] = (u16)f2bf(W[(size_t)(kb + j) * 128 + nn]);

    u16* dst = wsb + (size_t)(c * 4 + kk) * 512 + (size_t)l * 8;
#pragma unroll
    for (int j = 0; j < 8; ++j) dst[j] = tmp[j];
}

// Barrier-free, wave-owned rows, 2-deep ping-pong register prefetch (R5
// structure), with the dual GEMM moved to the MFMA pipe (bf16 16x16x32).
__global__ __launch_bounds__(TPB, 3) void fused_median_gemm(
    const float* __restrict__ x,
    const float* __restrict__ neigh,
    const u16*   __restrict__ wfrag,   // pre-swizzled bf16 weight fragments
    const float* __restrict__ bias,
    float* __restrict__ out,
    int N)
{
    __shared__ __align__(16) u16 xs[4][8][F];   // 8 KB (bf16)
    __shared__ __align__(16) u16 ms[4][8][F];   // 8 KB (bf16)

    const int tid  = threadIdx.x;
    const int wv   = tid >> 6;                  // wave id 0..3
    const int lane = tid & 63;                  // feature-pair index in phase A
    const int row0 = blockIdx.x * BR + wv * 8;

    const int rmax = N - 1;
    auto rw = [&](int rl) { int r = row0 + rl; return r > rmax ? rmax : r; };

    // ---------- Phase A: pipelined rank-16-of-32 over this wave's 8 rows ----------
    {
        f32x2 A0[16], B0[16], A1[16], B1[16];
        f32x2 x0, x1;

        issue_row(neigh, x, rw(0), lane, A0, B0, x0);
#pragma unroll
        for (int p = 0; p < 4; ++p) {
            issue_row(neigh, x, rw(2 * p + 1), lane, A1, B1, x1);   // prefetch odd row
            select_store(A0, B0, x0, &ms[wv][2 * p][0], &xs[wv][2 * p][0], lane);
            if (p < 3)
                issue_row(neigh, x, rw(2 * p + 2), lane, A0, B0, x0); // prefetch even row
            select_store(A1, B1, x1, &ms[wv][2 * p + 1][0], &xs[wv][2 * p + 1][0], lane);
        }
    }

    // drain this wave's LDS writes only (NOT vmcnt, NOT a barrier)
    asm volatile("s_waitcnt lgkmcnt(0)" ::: "memory");

    // ---------- Phase B: dual GEMM on the matrix pipe ----------
    // mfma_f32_16x16x32_bf16 lane mapping (m89/m92-verified):
    //   A: row = lane&15, k = (lane>>4)*8 + j   (8 contiguous bf16 -> b128)
    //   B: col = lane&15, k = (lane>>4)*8 + j   (pre-swizzled in wfrag)
    //   D: col = lane&15, row = (lane>>4)*4 + reg
    // Wave has 8 rows; rows 8..15 of the A tile duplicate rows 0..7 (lane&7),
    // their outputs are simply not stored.
    const int arow = lane & 7;
    const int ag   = lane >> 4;

    bf16x8 ax[4], am[4];
#pragma unroll
    for (int kk = 0; kk < 4; ++kk) {
        ax[kk] = *(const bf16x8*)&xs[wv][arow][kk * 32 + ag * 8];
        am[kk] = *(const bf16x8*)&ms[wv][arow][kk * 32 + ag * 8];
    }

    const bf16x8* __restrict__ wsf = (const bf16x8*)wfrag;
    const int dcol = lane & 15;            // D col within tile
    const int drow = (lane >> 4) * 4;      // D row base (store only if < 8)

#pragma unroll 4
    for (int c = 0; c < 16; ++c) {
        f32x4 acc = f32x4{0.f, 0.f, 0.f, 0.f};
#pragma unroll
        for (int kk = 0; kk < 4; ++kk) {
            const bf16x8 b = wsf[(c * 4 + kk) * 64 + lane];
            acc = __builtin_amdgcn_mfma_f32_16x16x32_bf16(
                      (c < 8) ? ax[kk] : am[kk], b, acc, 0, 0, 0);
        }
        const int col = c * 16 + dcol;
        const float bb = bias[col];
        if (lane < 32) {                   // rows 0..7 only
#pragma unroll
            for (int reg = 0; reg < 4; ++reg) {
                int row = row0 + drow + reg;
                if (row > rmax) row = rmax;   // tail: identical duplicate store
                const float o = fmaxf(acc[reg] + bb, 0.f);
                __builtin_nontemporal_store(o, &out[(size_t)row * 256 + col]);
            }
        }
    }
}

} // namespace

extern "C" void kernel_launch(void* const* d_in, const int* in_sizes, int n_in,
                              void* d_out, int out_size, void* d_ws, size_t ws_size,
                              hipStream_t stream) {
    const float* x     = (const float*)d_in[0];
    const float* neigh = (const float*)d_in[1];
    const float* Ks    = (const float*)d_in[2];
    const float* Kn    = (const float*)d_in[3];
    const float* bias  = (const float*)d_in[4];
    float* out = (float*)d_out;
    u16*   wsb = (u16*)d_ws;          // 64 KB of bf16 weight fragments

    const int N = in_sizes[0] / F;    // 50000

    hipLaunchKernelGGL(convert_weights, dim3(16), dim3(256), 0, stream,
                       Ks, Kn, wsb);

    const int grid = (N + BR - 1) / BR;
    hipLaunchKernelGGL(fused_median_gemm, dim3(grid), dim3(TPB), 0, stream,
                       x, neigh, wsb, bias, out, N);
}

// Round 9
// 182.441 us; speedup vs baseline: 1.1967x; 1.0573x over previous
//
#include <hip/hip_runtime.h>

namespace {

typedef float f32x4 __attribute__((ext_vector_type(4)));

constexpr int S   = 32;    // neighbors
constexpr int F   = 128;   // features
constexpr int BR  = 32;    // rows per block (8 per wave)
constexpr int TPB = 256;   // 4 waves

// ---- Batcher odd-even mergesort network for 16 elements (63 CEs) ----
struct CEPair { int a, b; };

constexpr int batcher_count16() {
  int n = 16, cnt = 0;
  for (int p = 1; p < n; p <<= 1)
    for (int k = p; k >= 1; k >>= 1)
      for (int j = k % p; j + k < n; j += 2 * k)
        for (int i = 0; i < k && i + j + k < n; ++i)
          if ((i + j) / (2 * p) == (i + j + k) / (2 * p))
            ++cnt;
  return cnt;
}
constexpr int NCE = batcher_count16();   // 63

struct Net16 { CEPair ce[NCE]; };

constexpr Net16 make_net16() {
  Net16 net{};
  int n = 16, c = 0;
  for (int p = 1; p < n; p <<= 1)
    for (int k = p; k >= 1; k >>= 1)
      for (int j = k % p; j + k < n; j += 2 * k)
        for (int i = 0; i < k && i + j + k < n; ++i)
          if ((i + j) / (2 * p) == (i + j + k) / (2 * p))
            net.ce[c++] = CEPair{i + j, i + j + k};
  return net;
}
constexpr Net16 NET16 = make_net16();

template<int T>
__device__ __forceinline__ void sort16(float (&v)[16]) {
  if constexpr (T < NCE) {
    constexpr int a = NET16.ce[T].a;
    constexpr int b = NET16.ce[T].b;
    float x = v[a], y = v[b];
    v[a] = fminf(x, y);
    v[b] = fmaxf(x, y);
    sort16<T + 1>(v);
  }
}

// Issue one HALF-row (32 neighbors x 64 features; lane = one feature):
// 32 nontemporal 256B loads + one x element. No waits here — the consumer's
// compiler-counted vmcnt waits only for ITS 33 loads, leaving the other
// slots' loads in flight (up to 3 half-rows = 24 KB lookahead per wave).
__device__ __forceinline__ void issue_half(const float* __restrict__ neigh,
                                           const float* __restrict__ x,
                                           int row, int h, int lane,
                                           float (&A)[16], float (&B)[16],
                                           float& xv)
{
    const float* nb = neigh + (size_t)row * (S * F) + h * 64 + lane;
#pragma unroll
    for (int s = 0; s < 16; ++s)
        A[s] = __builtin_nontemporal_load(nb + s * F);
#pragma unroll
    for (int s = 0; s < 16; ++s)
        B[s] = __builtin_nontemporal_load(nb + (s + 16) * F);
    xv = x[(size_t)row * F + h * 64 + lane];
}

// rank-16 (0-indexed) of 32 = min_{i=1..16} max(A[i-1], B[16-i])
__device__ __forceinline__ void select_store(float (&A)[16], float (&B)[16],
                                             float xv,
                                             float* __restrict__ msrow,
                                             float* __restrict__ xsrow,
                                             int h, int lane)
{
    sort16<0>(A);
    sort16<0>(B);
#pragma unroll
    for (int q = 0; q < 16; ++q) A[q] = fmaxf(A[q], B[15 - q]);
#pragma unroll
    for (int st = 8; st >= 1; st >>= 1)
#pragma unroll
        for (int q = 0; q < st; ++q) A[q] = fminf(A[q], A[q + st]);
    msrow[h * 64 + lane] = A[0];
    xsrow[h * 64 + lane] = xv;
}

// Barrier-free, wave-owned rows. Phase A: 16 half-row chunks in a 4-deep
// slot rotation — 3 chunks (24 KB) always in flight while one sorts.
__global__ __launch_bounds__(TPB, 3) void fused_median_gemm(
    const float* __restrict__ x,
    const float* __restrict__ neigh,
    const float* __restrict__ Ks,
    const float* __restrict__ Kn,
    const float* __restrict__ bias,
    float* __restrict__ out,
    int N)
{
    __shared__ __align__(16) float xs[4][8][F];   // 16 KB
    __shared__ __align__(16) float ms[4][8][F];   // 16 KB

    const int tid  = threadIdx.x;
    const int wv   = tid >> 6;                    // wave id 0..3
    const int lane = tid & 63;                    // feature within half-row
    const int row0 = blockIdx.x * BR + wv * 8;

    const int rmax = N - 1;
    auto rw = [&](int hp) { int r = row0 + (hp >> 1); return r > rmax ? rmax : r; };

    // ---------- Phase A: 4-deep pipelined rank-16-of-32 (16 half-row chunks) ----------
    {
        float A0[16], B0[16], A1[16], B1[16];
        float A2[16], B2[16], A3[16], B3[16];
        float x0, x1, x2, x3;

        issue_half(neigh, x, rw(0), 0, lane, A0, B0, x0);
        issue_half(neigh, x, rw(1), 1, lane, A1, B1, x1);
        issue_half(neigh, x, rw(2), 0, lane, A2, B2, x2);

#pragma unroll 1
        for (int q = 0; q < 4; ++q) {
            const int hp = q * 4;
            // step 0: work slot0, prefetch hp+3 -> slot3
            issue_half(neigh, x, rw(hp + 3), (hp + 3) & 1, lane, A3, B3, x3);
            select_store(A0, B0, x0, &ms[wv][hp >> 1][0], &xs[wv][hp >> 1][0],
                         hp & 1, lane);
            // step 1: work slot1, prefetch hp+4 -> slot0
            if (hp + 4 < 16)
                issue_half(neigh, x, rw(hp + 4), (hp + 4) & 1, lane, A0, B0, x0);
            select_store(A1, B1, x1, &ms[wv][(hp + 1) >> 1][0], &xs[wv][(hp + 1) >> 1][0],
                         (hp + 1) & 1, lane);
            // step 2: work slot2, prefetch hp+5 -> slot1
            if (hp + 5 < 16)
                issue_half(neigh, x, rw(hp + 5), (hp + 5) & 1, lane, A1, B1, x1);
            select_store(A2, B2, x2, &ms[wv][(hp + 2) >> 1][0], &xs[wv][(hp + 2) >> 1][0],
                         (hp + 2) & 1, lane);
            // step 3: work slot3, prefetch hp+6 -> slot2
            if (hp + 6 < 16)
                issue_half(neigh, x, rw(hp + 6), (hp + 6) & 1, lane, A2, B2, x2);
            select_store(A3, B3, x3, &ms[wv][(hp + 3) >> 1][0], &xs[wv][(hp + 3) >> 1][0],
                         (hp + 3) & 1, lane);
        }
    }

    // drain this wave's LDS writes only (NOT vmcnt, NOT a barrier)
    asm volatile("s_waitcnt lgkmcnt(0)" ::: "memory");

    // ---------- Phase B: GEMM for this wave's 8 rows ----------
    // lane -> 4 output cols; lanes 0..31 self-half, 32..63 neigh-half
    const bool self_half = (lane < 32);
    const float* __restrict__ W = self_half ? Ks : Kn;
    const int wcol = (lane * 4) & 127;
    const float* lin = self_half ? &xs[wv][0][0] : &ms[wv][0][0];

    f32x4 acc[8];
#pragma unroll
    for (int r = 0; r < 8; ++r) acc[r] = f32x4{0.f, 0.f, 0.f, 0.f};

#pragma unroll 4
    for (int k4 = 0; k4 < 32; ++k4) {
        f32x4 wv4[4];
#pragma unroll
        for (int dk = 0; dk < 4; ++dk)
            wv4[dk] = *(const f32x4*)&W[(k4 * 4 + dk) * 128 + wcol];

        f32x4 xr[8];
#pragma unroll
        for (int r = 0; r < 8; ++r)
            xr[r] = *(const f32x4*)&lin[r * F + k4 * 4];   // wave-broadcast LDS read

#pragma unroll
        for (int r = 0; r < 8; ++r) {
#pragma unroll
            for (int dk = 0; dk < 4; ++dk) {
                const float s = xr[r][dk];
                acc[r].x = fmaf(s, wv4[dk].x, acc[r].x);
                acc[r].y = fmaf(s, wv4[dk].y, acc[r].y);
                acc[r].z = fmaf(s, wv4[dk].z, acc[r].z);
                acc[r].w = fmaf(s, wv4[dk].w, acc[r].w);
            }
        }
    }

    const f32x4 bv = *(const f32x4*)&bias[lane * 4];
#pragma unroll
    for (int r = 0; r < 8; ++r) {
        int row = row0 + r;
        if (row > rmax) row = rmax;   // duplicate store of identical values; benign
        f32x4 o;
        o.x = fmaxf(acc[r].x + bv.x, 0.f);
        o.y = fmaxf(acc[r].y + bv.y, 0.f);
        o.z = fmaxf(acc[r].z + bv.z, 0.f);
        o.w = fmaxf(acc[r].w + bv.w, 0.f);
        __builtin_nontemporal_store(o, (f32x4*)&out[(size_t)row * 256 + lane * 4]);
    }
}

} // namespace

extern "C" void kernel_launch(void* const* d_in, const int* in_sizes, int n_in,
                              void* d_out, int out_size, void* d_ws, size_t ws_size,
                              hipStream_t stream) {
    const float* x     = (const float*)d_in[0];
    const float* neigh = (const float*)d_in[1];
    const float* Ks    = (const float*)d_in[2];
    const float* Kn    = (const float*)d_in[3];
    const float* bias  = (const float*)d_in[4];
    float* out = (float*)d_out;

    const int N = in_sizes[0] / F;   // 50000
    const int grid = (N + BR - 1) / BR;
    hipLaunchKernelGGL(fused_median_gemm, dim3(grid), dim3(TPB), 0, stream,
                       x, neigh, Ks, Kn, bias, out, N);
}